// Round 1
// baseline (8266.232 us; speedup 1.0000x reference)
//
#include <hip/hip_runtime.h>
#include <hip/hip_bf16.h>

// Sizes (fixed for this problem)
#define BB 32
#define TT 512
#define HH 1024
#define II 1024
#define G4H 4096          // 4*H
#define BH  (BB * HH)     // 32768
#define TH  ((size_t)TT * HH)  // 524288 = 1<<19

typedef __bf16 bf16x8_t __attribute__((ext_vector_type(8)));
typedef float f32x4_t __attribute__((ext_vector_type(4)));

// ---------------------------------------------------------------------------
// Init: bias0/1 = bih + bhh ; zero c0, c1, zero-h buffer
// ---------------------------------------------------------------------------
__global__ void init_misc(const float* __restrict__ bih0, const float* __restrict__ bhh0,
                          const float* __restrict__ bih1, const float* __restrict__ bhh1,
                          float* __restrict__ bias0, float* __restrict__ bias1,
                          float* __restrict__ c0, float* __restrict__ c1,
                          __hip_bfloat16* __restrict__ zbuf) {
    int i = blockIdx.x * 256 + threadIdx.x;   // grid covers 32768
    if (i < G4H) {
        bias0[i] = bih0[i] + bhh0[i];
        bias1[i] = bih1[i] + bhh1[i];
    }
    if (i < BH) {
        c0[i] = 0.f;
        c1[i] = 0.f;
        zbuf[i] = __float2bfloat16(0.f);
    }
}

// ---------------------------------------------------------------------------
// Weight shuffle: fp32 [4096][1024] -> bf16 in MFMA-B-fragment order:
//   dst[((wg*32 + kb)*64 + lane)*8 + jj] = W[row][col]
//   n = lane&15, q = lane>>4, row = (n>>2)*1024 + wg*4 + (n&3), col = kb*32 + q*8 + jj
// Hot-loop loads become lane-consecutive 16B chunks (perfectly coalesced).
// ---------------------------------------------------------------------------
__global__ void shuffle_w(const float* __restrict__ src, __hip_bfloat16* __restrict__ dst) {
    size_t i = (size_t)blockIdx.x * 256 + threadIdx.x;   // 0 .. 4M-1
    int jj   = (int)(i & 7);
    int lane = (int)((i >> 3) & 63);
    int kb   = (int)((i >> 9) & 31);
    int wg   = (int)(i >> 14);
    int n = lane & 15, q = lane >> 4;
    int row = (n >> 2) * 1024 + wg * 4 + (n & 3);
    int col = kb * 32 + q * 8 + jj;
    dst[i] = __float2bfloat16(src[(size_t)row * II + col]);
}

// ---------------------------------------------------------------------------
// x [B][T][I] fp32 -> xb [T][B][I] bf16 (time-major so each step slice is contiguous)
// ---------------------------------------------------------------------------
__global__ void convert_x(const float* __restrict__ x, __hip_bfloat16* __restrict__ xb) {
    size_t i = (size_t)blockIdx.x * 256 + threadIdx.x;   // over T*B*I = 16.7M
    int ii = (int)(i & 1023);
    int b  = (int)((i >> 10) & 31);
    int t  = (int)(i >> 15);
    xb[i] = __float2bfloat16(x[((size_t)b * TT + t) * II + ii]);
}

// ---------------------------------------------------------------------------
// One LSTM timestep, both GEMMs fused + pointwise + (optional) residual out.
// grid = 256 WGs (WG w owns h-dims [4w,4w+4) -> 16 gate rows), 256 threads.
// wave = (p, mtile): p=0 input GEMM (A=xt), p=1 hidden GEMM (A=hprev);
// mtile picks batches 0-15 / 16-31. A-frags straight from global (zero reuse
// inside the WG -> LDS staging would be pure overhead); B-frags from the
// pre-shuffled weight layout. Partials meet in LDS, 128 threads do the gates.
// ---------------------------------------------------------------------------
__global__ __launch_bounds__(256)
void lstm_step(const __hip_bfloat16* __restrict__ xt,     // [B][1024] bf16
               const __hip_bfloat16* __restrict__ hprev,  // [B][1024] bf16
               const __hip_bfloat16* __restrict__ Wx,     // shuffled bf16
               const __hip_bfloat16* __restrict__ Wh,     // shuffled bf16
               const float* __restrict__ bias,            // [4096] (bih+bhh)
               float* __restrict__ c,                     // [B][1024] fp32 state
               __hip_bfloat16* __restrict__ hout,         // [B][1024] bf16
               float* __restrict__ outp,                  // null for layer0; else out + t*H
               const __hip_bfloat16* __restrict__ h0res)  // residual source (layer1)
{
    const int wg   = blockIdx.x;
    const int tid  = threadIdx.x;
    const int wave = tid >> 6, lane = tid & 63;
    const int p     = wave >> 1;
    const int mtile = wave & 1;
    const int n = lane & 15, q = lane >> 4;

    __shared__ float psum[2][32][17];   // +1 pad: dodge bank conflicts

    const __bf16* A = (const __bf16*)(p ? hprev : xt);
    const __bf16* W = (const __bf16*)(p ? Wh : Wx);
    const __bf16* a_ptr = A + (mtile * 16 + n) * 1024 + q * 8;
    const __bf16* b_ptr = W + (size_t)wg * 16384 + lane * 8;

    f32x4_t acc = {0.f, 0.f, 0.f, 0.f};
#pragma unroll
    for (int kb = 0; kb < 32; ++kb) {
        bf16x8_t av = *(const bf16x8_t*)(a_ptr + kb * 32);
        bf16x8_t bv = *(const bf16x8_t*)(b_ptr + kb * 512);
        acc = __builtin_amdgcn_mfma_f32_16x16x32_bf16(av, bv, acc, 0, 0, 0);
    }

    // C/D layout: col = lane&15 (=n), row = q*4 + r
    const int mbase = mtile * 16 + q * 4;
#pragma unroll
    for (int r = 0; r < 4; ++r) psum[p][mbase + r][n] = acc[r];
    __syncthreads();

    if (tid < 128) {
        const int b = tid >> 2, j = tid & 3;
        const int dim = (wg << 2) + j;
        float gi = psum[0][b][j]      + psum[1][b][j]      + bias[dim];
        float gf = psum[0][b][4 + j]  + psum[1][b][4 + j]  + bias[1024 + dim];
        float gg = psum[0][b][8 + j]  + psum[1][b][8 + j]  + bias[2048 + dim];
        float go = psum[0][b][12 + j] + psum[1][b][12 + j] + bias[3072 + dim];
        float si = 1.f / (1.f + __expf(-gi));
        float sf = 1.f / (1.f + __expf(-gf));
        float so = 1.f / (1.f + __expf(-go));
        float tg = 2.f / (1.f + __expf(-2.f * gg)) - 1.f;   // tanh
        const int ci = (b << 10) + dim;
        float cv = sf * c[ci] + si * tg;
        c[ci] = cv;
        float tc = 2.f / (1.f + __expf(-2.f * cv)) - 1.f;   // tanh
        float hv = so * tc;
        hout[ci] = __float2bfloat16(hv);
        if (outp) {
            outp[((size_t)b << 19) + dim] = __bfloat162float(h0res[ci]) + hv;
        }
    }
}

// ---------------------------------------------------------------------------
// Host side
// ---------------------------------------------------------------------------
extern "C" void kernel_launch(void* const* d_in, const int* in_sizes, int n_in,
                              void* d_out, int out_size, void* d_ws, size_t ws_size,
                              hipStream_t stream) {
    const float* x    = (const float*)d_in[0];
    const float* Wih0 = (const float*)d_in[1];
    const float* Whh0 = (const float*)d_in[2];
    const float* bih0 = (const float*)d_in[3];
    const float* bhh0 = (const float*)d_in[4];
    const float* Wih1 = (const float*)d_in[5];
    const float* Whh1 = (const float*)d_in[6];
    const float* bih1 = (const float*)d_in[7];
    const float* bhh1 = (const float*)d_in[8];
    float* out = (float*)d_out;

    // Workspace carve (bytes). Total ~96.5 MiB.
    uint8_t* w = (uint8_t*)d_ws;
    const size_t WMAT = (size_t)G4H * HH * 2;      // 8 MiB bf16 per weight matrix
    __hip_bfloat16* Wxs0 = (__hip_bfloat16*)(w);
    __hip_bfloat16* Whs0 = (__hip_bfloat16*)(w + WMAT);
    __hip_bfloat16* Wxs1 = (__hip_bfloat16*)(w + 2 * WMAT);
    __hip_bfloat16* Whs1 = (__hip_bfloat16*)(w + 3 * WMAT);
    __hip_bfloat16* xb    = (__hip_bfloat16*)(w + 4 * WMAT);                    // [T][B][I] bf16
    __hip_bfloat16* h0seq = (__hip_bfloat16*)(w + 4 * WMAT + TH * BB / 512 * 2);// see below
    // simpler explicit offsets:
    {
        size_t off = 4 * WMAT;                       // 33,554,432
        xb    = (__hip_bfloat16*)(w + off); off += (size_t)TT * BB * II * 2;  // +33,554,432
        h0seq = (__hip_bfloat16*)(w + off);
    }
    size_t off = 4 * WMAT + (size_t)TT * BB * II * 2;
    h0seq = (__hip_bfloat16*)(w + off); off += (size_t)TT * BB * HH * 2;      // +33,554,432
    __hip_bfloat16* h1buf = (__hip_bfloat16*)(w + off); off += 2 * (size_t)BH * 2;
    __hip_bfloat16* zbuf  = (__hip_bfloat16*)(w + off); off += (size_t)BH * 2;
    float* c0    = (float*)(w + off); off += (size_t)BH * 4;
    float* c1    = (float*)(w + off); off += (size_t)BH * 4;
    float* bias0 = (float*)(w + off); off += (size_t)G4H * 4;
    float* bias1 = (float*)(w + off); off += (size_t)G4H * 4;
    (void)ws_size; (void)n_in; (void)in_sizes; (void)out_size;

    // --- init / conversion ---
    init_misc<<<BH / 256, 256, 0, stream>>>(bih0, bhh0, bih1, bhh1, bias0, bias1, c0, c1, zbuf);
    shuffle_w<<<(G4H * HH) / 256, 256, 0, stream>>>(Wih0, Wxs0);
    shuffle_w<<<(G4H * HH) / 256, 256, 0, stream>>>(Whh0, Whs0);
    shuffle_w<<<(G4H * HH) / 256, 256, 0, stream>>>(Wih1, Wxs1);
    shuffle_w<<<(G4H * HH) / 256, 256, 0, stream>>>(Whh1, Whs1);
    convert_x<<<(TT * BB * II) / 256, 256, 0, stream>>>(x, xb);

    // --- layer 0: 512 sequential steps; h0seq [T][B][H] bf16 ---
    for (int t = 0; t < TT; ++t) {
        const __hip_bfloat16* hp = (t == 0) ? zbuf : (h0seq + (size_t)(t - 1) * BH);
        lstm_step<<<256, 256, 0, stream>>>(xb + (size_t)t * BH, hp, Wxs0, Whs0, bias0,
                                           c0, h0seq + (size_t)t * BH,
                                           (float*)nullptr, (const __hip_bfloat16*)nullptr);
    }

    // --- layer 1: 512 sequential steps; input = h0seq[t]; fused residual out ---
    for (int t = 0; t < TT; ++t) {
        const __hip_bfloat16* hp = (t == 0) ? zbuf : (h1buf + (size_t)((t - 1) & 1) * BH);
        lstm_step<<<256, 256, 0, stream>>>(h0seq + (size_t)t * BH, hp, Wxs1, Whs1, bias1,
                                           c1, h1buf + (size_t)(t & 1) * BH,
                                           out + (size_t)t * HH, h0seq + (size_t)t * BH);
    }
}